// Round 1
// baseline (250.777 us; speedup 1.0000x reference)
//
#include <hip/hip_runtime.h>
#include <hip/hip_bf16.h>

// RGCN: N=4096, D=128, R=8, B=8, two layers + LN(+ReLU).
// Strategy: dense per-relation matmul via bf16 MFMA with register-level
// relation masking of the adjacency fragments.

#define NN 4096
#define DD 128

typedef __attribute__((ext_vector_type(8))) short  s16x8;   // storage for 8 bf16
typedef __attribute__((ext_vector_type(8))) __bf16 bf16v8;  // MFMA operand type
typedef __attribute__((ext_vector_type(4))) float  f32x4;
typedef __attribute__((ext_vector_type(4))) int    i32x4;

__device__ inline short f2bf(float f) {            // f32 -> bf16 bits, RNE
  union { float f; unsigned u; } v; v.f = f;
  unsigned r = (v.u + 0x7FFFu + ((v.u >> 16) & 1u)) >> 16;
  return (short)r;
}

__device__ inline f32x4 mfma16(s16x8 a, s16x8 b, f32x4 c) {
  return __builtin_amdgcn_mfma_f32_16x16x32_bf16(
      __builtin_bit_cast(bf16v8, a), __builtin_bit_cast(bf16v8, b), c, 0, 0, 0);
}

// ---------------------------------------------------------------------------
// K1: w_r = sum_b weights[r,b]*bases[b]  (plus r==8 -> W_self), written
// pre-fragmented as B-operand frags: [layer][r(9)][s(4 k-steps)][t(8 o-tiles)]
// [lane(64)][e(8)], element = w[i = 32s+8*(l>>4)+e][o = 16t+(l&15)].
// ---------------------------------------------------------------------------
__global__ void prep_w(const float* __restrict__ b1, const float* __restrict__ w1,
                       const float* __restrict__ ws1,
                       const float* __restrict__ b2, const float* __restrict__ w2,
                       const float* __restrict__ ws2,
                       short* __restrict__ wfrag) {
  int tid = blockIdx.x * 256 + threadIdx.x;   // 0..36863 (2 layers x 18432)
  int layer = (tid >= 18432);
  int t0 = tid - layer * 18432;
  int lane = t0 & 63;
  int t = (t0 >> 6) & 7;
  int s = (t0 >> 9) & 3;
  int r = t0 >> 11;                            // 0..8
  const float* bases = layer ? b2 : b1;
  const float* wts   = layer ? w2 : w1;
  const float* wself = layer ? ws2 : ws1;
  int o  = t * 16 + (lane & 15);
  int i0 = s * 32 + 8 * (lane >> 4);
  short v[8];
#pragma unroll
  for (int e = 0; e < 8; ++e) {
    int i = i0 + e;
    float a;
    if (r < 8) {
      a = 0.f;
#pragma unroll
      for (int b = 0; b < 8; ++b)
        a += wts[r * 8 + b] * bases[((size_t)b * 128 + i) * 128 + o];
    } else {
      a = wself[(size_t)i * 128 + o];
    }
    v[e] = f2bf(a);
  }
  *(s16x8*)(wfrag + (size_t)tid * 8) = *(s16x8*)v;
}

// ---------------------------------------------------------------------------
// K2: xw_r = xin @ w_r for r=0..7 -> xwfrag in aggregation-B-frag layout
//     [r][mstep(128)][t(8)][lane(64)][e(8)], elem = xw[r][32*ms+8*(l>>4)+e][16t+(l&15)]
//     r==8: hacc = xin @ W_self + bias   (f32, plain stores; base for atomics)
// One wave per (m-tile of 32 rows, r). 4 waves/block, grid 288.
// ---------------------------------------------------------------------------
__global__ void xw_gemm(const float* __restrict__ xin, const short* __restrict__ wfrag,
                        short* __restrict__ xwfrag, float* __restrict__ hacc,
                        const float* __restrict__ bias) {
  __shared__ short lds[4][32 * 128];
  int w = threadIdx.x >> 6, lane = threadIdx.x & 63;
  int widx = blockIdx.x * 4 + w;   // 0..1151
  int m = widx & 127;              // 32-row tile
  int r = widx >> 7;               // 0..8
  int l15 = lane & 15, l4 = lane >> 4;

  f32x4 acc[2][8] = {};

#pragma unroll
  for (int s = 0; s < 4; ++s) {
    s16x8 A[2];
#pragma unroll
    for (int nt = 0; nt < 2; ++nt) {
      const float* xp = xin + (size_t)(m * 32 + nt * 16 + l15) * 128 + s * 32 + 8 * l4;
      f32x4 f0 = *(const f32x4*)xp;
      f32x4 f1 = *(const f32x4*)(xp + 4);
      s16x8 av;
#pragma unroll
      for (int e = 0; e < 4; ++e) av[e] = f2bf(f0[e]);
#pragma unroll
      for (int e = 0; e < 4; ++e) av[4 + e] = f2bf(f1[e]);
      A[nt] = av;
    }
    const short* bp = wfrag + ((size_t)(r * 4 + s) * 8) * 512 + lane * 8;
#pragma unroll
    for (int t = 0; t < 8; ++t) {
      s16x8 B = *(const s16x8*)(bp + t * 512);
      acc[0][t] = mfma16(A[0], B, acc[0][t]);
      acc[1][t] = mfma16(A[1], B, acc[1][t]);
    }
  }

  if (r == 8) {
    // self-loop: f32 store (+bias). D layout: row=4*(l>>4)+j, col=l&15 (m89).
#pragma unroll
    for (int nt = 0; nt < 2; ++nt)
#pragma unroll
      for (int t = 0; t < 8; ++t)
#pragma unroll
        for (int j = 0; j < 4; ++j) {
          int row = m * 32 + nt * 16 + 4 * l4 + j;
          int col = t * 16 + l15;
          hacc[(size_t)row * 128 + col] = acc[nt][t][j] + bias[col];
        }
  } else {
    // shuffle D -> B-frag order through LDS, store bf16
#pragma unroll
    for (int nt = 0; nt < 2; ++nt)
#pragma unroll
      for (int t = 0; t < 8; ++t)
#pragma unroll
        for (int j = 0; j < 4; ++j)
          lds[w][(nt * 16 + 4 * l4 + j) * 128 + t * 16 + l15] = f2bf(acc[nt][t][j]);
    __syncthreads();   // all waves of a block take this branch (r grouping aligns)
#pragma unroll
    for (int t = 0; t < 8; ++t) {
      short v[8];
#pragma unroll
      for (int e = 0; e < 8; ++e) v[e] = lds[w][(8 * l4 + e) * 128 + t * 16 + l15];
      *(s16x8*)(xwfrag + ((size_t)(r * 128 + m) * 8 + t) * 512 + lane * 8) = *(s16x8*)v;
    }
  }
}

// ---------------------------------------------------------------------------
// K3: hacc += sum_r (adj .* (et==r)) @ xw_r
// Block = 4 waves, each wave owns 64 rows (4 subtiles of 16), all 8 relations,
// o = full 128 (8 o-tiles). Grid = 16 row-blocks x 32 k-chunks = 512 blocks.
// A-frags loaded from global (stream-once), masked in registers per relation.
// ---------------------------------------------------------------------------
__launch_bounds__(256, 2)
__global__ void agg_kernel(const float* __restrict__ adj, const int* __restrict__ et,
                           const short* __restrict__ xwfrag, float* __restrict__ hacc) {
  int w = threadIdx.x >> 6, lane = threadIdx.x & 63;
  int rowblk = blockIdx.x & 15;
  int kc = blockIdx.x >> 4;          // 0..31, k-chunk of 128 m (4 m-steps)
  int rowbase = rowblk * 256 + w * 64;
  int l15 = lane & 15, l4 = lane >> 4;

  f32x4 acc[4][8] = {};

  for (int ms = 0; ms < 4; ++ms) {
    int gm = kc * 4 + ms;            // global 32-wide m-step
    int mofs = gm * 32 + 8 * l4;
    s16x8 a[4]; i32x4 elo[4], ehi[4];
#pragma unroll
    for (int nt = 0; nt < 4; ++nt) {
      size_t rbase = (size_t)(rowbase + nt * 16 + l15) * 4096 + mofs;
      f32x4 f0 = *(const f32x4*)(adj + rbase);
      f32x4 f1 = *(const f32x4*)(adj + rbase + 4);
      elo[nt] = *(const i32x4*)(et + rbase);
      ehi[nt] = *(const i32x4*)(et + rbase + 4);
      s16x8 av;
#pragma unroll
      for (int e = 0; e < 4; ++e) av[e] = f2bf(f0[e]);
#pragma unroll
      for (int e = 0; e < 4; ++e) av[4 + e] = f2bf(f1[e]);
      a[nt] = av;
    }
#pragma unroll
    for (int r = 0; r < 8; ++r) {
      const short* bp = xwfrag + ((size_t)(r * 128 + gm) * 8) * 512 + lane * 8;
      s16x8 b[8];
#pragma unroll
      for (int t = 0; t < 8; ++t) b[t] = *(const s16x8*)(bp + t * 512);
#pragma unroll
      for (int nt = 0; nt < 4; ++nt) {
        s16x8 mfr;
#pragma unroll
        for (int e = 0; e < 4; ++e) mfr[e] = (elo[nt][e] == r) ? a[nt][e] : (short)0;
#pragma unroll
        for (int e = 0; e < 4; ++e) mfr[4 + e] = (ehi[nt][e] == r) ? a[nt][4 + e] : (short)0;
#pragma unroll
        for (int t = 0; t < 8; ++t)
          acc[nt][t] = mfma16(mfr, b[t], acc[nt][t]);
      }
    }
  }

  // epilogue: k-split partials -> atomic f32 add
#pragma unroll
  for (int nt = 0; nt < 4; ++nt)
#pragma unroll
    for (int t = 0; t < 8; ++t)
#pragma unroll
      for (int j = 0; j < 4; ++j) {
        int row = rowbase + nt * 16 + 4 * l4 + j;
        int col = t * 16 + l15;
        unsafeAtomicAdd(&hacc[(size_t)row * 128 + col], acc[nt][t][j]);
      }
}

// ---------------------------------------------------------------------------
// K4: row LayerNorm (+optional ReLU). One wave per row, 2 elems/lane.
// ---------------------------------------------------------------------------
__global__ void ln_kernel(const float* __restrict__ h, const float* __restrict__ gamma,
                          const float* __restrict__ beta, float* __restrict__ out,
                          int relu) {
  int row  = blockIdx.x * 4 + (threadIdx.x >> 6);
  int lane = threadIdx.x & 63;
  float2 v = *(const float2*)&h[(size_t)row * 128 + lane * 2];
  float s  = v.x + v.y;
  float sq = v.x * v.x + v.y * v.y;
#pragma unroll
  for (int off = 32; off; off >>= 1) {
    s  += __shfl_xor(s,  off);
    sq += __shfl_xor(sq, off);
  }
  float mu  = s * (1.f / 128.f);
  float var = sq * (1.f / 128.f) - mu * mu;
  float inv = rsqrtf(var + 1e-5f);
  float y0 = (v.x - mu) * inv * gamma[lane * 2]     + beta[lane * 2];
  float y1 = (v.y - mu) * inv * gamma[lane * 2 + 1] + beta[lane * 2 + 1];
  if (relu) { y0 = fmaxf(y0, 0.f); y1 = fmaxf(y1, 0.f); }
  float2 o; o.x = y0; o.y = y1;
  *(float2*)&out[(size_t)row * 128 + lane * 2] = o;
}

// ---------------------------------------------------------------------------
extern "C" void kernel_launch(void* const* d_in, const int* in_sizes, int n_in,
                              void* d_out, int out_size, void* d_ws, size_t ws_size,
                              hipStream_t stream) {
  const float* x      = (const float*)d_in[0];
  const float* adj    = (const float*)d_in[1];
  const int*   et     = (const int*)d_in[2];
  const float* bases1 = (const float*)d_in[3];
  const float* wts1   = (const float*)d_in[4];
  const float* wself1 = (const float*)d_in[5];
  const float* bself1 = (const float*)d_in[6];
  const float* bases2 = (const float*)d_in[7];
  const float* wts2   = (const float*)d_in[8];
  const float* wself2 = (const float*)d_in[9];
  const float* bself2 = (const float*)d_in[10];
  const float* gamma1 = (const float*)d_in[11];
  const float* beta1  = (const float*)d_in[12];
  const float* gamma2 = (const float*)d_in[13];
  const float* beta2  = (const float*)d_in[14];

  char* ws = (char*)d_ws;
  short* wfrag  = (short*)(ws);                               // 589824 B (2 layers)
  short* xwfrag = (short*)(ws + 589824);                      // 8 MB
  float* hacc   = (float*)(ws + 589824 + 8388608);            // 2 MB
  float* h1     = (float*)(ws + 589824 + 8388608 + 2097152);  // 2 MB

  prep_w<<<144, 256, 0, stream>>>(bases1, wts1, wself1, bases2, wts2, wself2, wfrag);

  // layer 1
  xw_gemm<<<288, 256, 0, stream>>>(x, wfrag, xwfrag, hacc, bself1);
  agg_kernel<<<512, 256, 0, stream>>>(adj, et, xwfrag, hacc);
  ln_kernel<<<1024, 256, 0, stream>>>(hacc, gamma1, beta1, h1, 1);

  // layer 2
  xw_gemm<<<288, 256, 0, stream>>>(h1, wfrag + 147456, xwfrag, hacc, bself2);
  agg_kernel<<<512, 256, 0, stream>>>(adj, et, xwfrag, hacc);
  ln_kernel<<<1024, 256, 0, stream>>>(hacc, gamma2, beta2, (float*)d_out, 0);
}